// Round 5
// baseline (149405.103 us; speedup 1.0000x reference)
//
#include <hip/hip_runtime.h>
#include <math.h>

#define NB 256   // batch
#define NN 256   // code length
#define NK 128   // info bits
#define ND 256   // embedding dim
#define NH 512   // hidden dim
#define NT 1024  // threads per block

// output layout (floats) in d_out, return order: x | f_out | u | p_u
#define OUT_X 0
#define OUT_F 65536
#define OUT_U 131072
#define OUT_P 196608

// ws layout (float offsets)
#define ECNT (255 * NB * ND)   // E levels 1..8: [lvlpos][batch][D]
#define HBASE ECNT
#define HCNT (32 * NB * NH)    // H chunk buffer: [pl][batch][H]
#define BAR_FOFF (HBASE + HCNT)

#define SCR_F 18432   // LDS scratch: A-tiles / k-split partials / cascade bufs
#define WT_F  8320    // LDS transposed weight tile (32 x 260 max)

__host__ __device__ __forceinline__ int loff(int d) { return 256 - (1 << (9 - d)); }

struct SMem {
  float scr[SCR_F];
  float wt[WT_F];
  int   L[16 * 256];     // per-group decision bits [batch_local][slot]
  float emb[2 * NH];     // label_emb[bit] @ bnW1[512:768]
  int   fmap[256];       // pos -> info index or -1
};

// ---- per-batch-group barrier (16 blocks), sense-reversing, agent scope ----
__device__ __forceinline__ void bgbar(unsigned* cnt, unsigned* gen) {
  __syncthreads();
  if (threadIdx.x == 0) {
    __threadfence();  // publish this XCD L2's dirty lines device-wide
    unsigned g = __hip_atomic_load(gen, __ATOMIC_RELAXED, __HIP_MEMORY_SCOPE_AGENT);
    unsigned a = __hip_atomic_fetch_add(cnt, 1u, __ATOMIC_ACQ_REL, __HIP_MEMORY_SCOPE_AGENT);
    if (a == 15u) {
      __hip_atomic_store(cnt, 0u, __ATOMIC_RELAXED, __HIP_MEMORY_SCOPE_AGENT);
      __hip_atomic_fetch_add(gen, 1u, __ATOMIC_RELEASE, __HIP_MEMORY_SCOPE_AGENT);
    } else {
      while (__hip_atomic_load(gen, __ATOMIC_ACQUIRE, __HIP_MEMORY_SCOPE_AGENT) == g) {
        __builtin_amdgcn_s_sleep(1);
      }
    }
    __threadfence();
  }
  __syncthreads();
  __threadfence();  // acquire: drop stale L1 lines before reading peers' data
}

__device__ __forceinline__ void writeOne(
    SMem* sm, int bg, int outMode, int pl, int bl, int col, float s,
    const float* __restrict__ bias, float* __restrict__ Hdst,
    float* __restrict__ Edst, int lofDst, int lofC, int pbase) {
  s += bias[col];
  if (outMode != 2) {
    if (outMode == 1) {
      const int bit = sm->L[bl * 256 + lofC + pbase + pl];
      s += sm->emb[bit * NH + col];
    }
    s = fmaxf(s, 0.f);
    Hdst[((size_t)pl * NB + bg * 16 + bl) * NH + col] = s;
  } else {
    Edst[((size_t)(lofDst + pbase + pl) * NB + bg * 16 + bl) * ND + col] = s;
  }
}

// One GEMM phase: OUT[R rows = 16 batches x (R/16) positions][CW cols of this
// col-slice], K=512, LDS-tiled in k-slabs of SK, micro-tile MxN, k-split G.
template <int R, int CW, int M, int N, int G, int SK>
__device__ void phase_gemm(
    SMem* sm, int tid, int bg, int cs,
    int inMode,  // 0 = E-pair gather, 1 = obs2 broadcast, 2 = H rows
    const float* __restrict__ srcE, const float* __restrict__ obs2,
    const float* __restrict__ Hsrc,
    const float* __restrict__ Wg, int ldw, const float* __restrict__ bias,
    int outMode,  // 0 = H(cn), 1 = H(bn,+emb), 2 = E
    float* __restrict__ Hdst, float* __restrict__ Edst,
    int lofDst, int lofC, int pbase) {
  static_assert((R / M) * (CW / N) * G == NT, "thread count");
  static_assert(R * (SK + 4) <= SCR_F, "A tile");
  static_assert(G == 1 || G * R * CW <= SCR_F, "parts");
  static_assert(CW * (SK + 4) <= WT_F, "W tile");
  constexpr int TC = CW / N;
  constexpr int TR = R / M;
  constexpr int KS = SK / G;
  constexpr int LDA = SK + 4;
  const int c0 = cs * CW;
  const int cq = tid % TC;
  const int rq = (tid / TC) % TR;
  const int g = tid / (TC * TR);
  float acc[M][N];
#pragma unroll
  for (int i = 0; i < M; ++i)
#pragma unroll
    for (int j = 0; j < N; ++j) acc[i][j] = 0.f;

  for (int k0 = 0; k0 < 512; k0 += SK) {
    // ---- stage A slab (R x SK) ----
    constexpr int NF4 = R * SK / 4;
    for (int i = tid; i < NF4; i += NT) {
      const int r = i / (SK / 4), f = i % (SK / 4);
      const int k = k0 + f * 4;
      const int pl = r >> 4, bl = r & 15;
      float4 v;
      if (inMode == 1) {
        v = *(const float4*)&obs2[k & 255];
      } else if (inMode == 0) {
        const int p2 = 2 * (pbase + pl) + (k >> 8);
        v = *(const float4*)&srcE[((size_t)p2 * NB + bg * 16 + bl) * ND + (k & 255)];
      } else {
        v = *(const float4*)&Hsrc[((size_t)pl * NB + bg * 16 + bl) * NH + k];
      }
      *(float4*)&sm->scr[r * LDA + f * 4] = v;
    }
    // ---- stage W^T slab (CW x SK) ----
    for (int i = tid; i < CW * SK; i += NT) {
      const int kk = i / CW, c = i % CW;
      sm->wt[c * LDA + kk] = Wg[(size_t)(k0 + kk) * ldw + c0 + c];
    }
    __syncthreads();
    // ---- compute ----
    {
      const int kb = g * KS;
#pragma unroll 8
      for (int kk = 0; kk < KS; kk += 4) {
        float4 a[M], w[N];
#pragma unroll
        for (int i = 0; i < M; ++i)
          a[i] = *(const float4*)&sm->scr[(rq * M + i) * LDA + kb + kk];
#pragma unroll
        for (int j = 0; j < N; ++j)
          w[j] = *(const float4*)&sm->wt[(cq * N + j) * LDA + kb + kk];
#pragma unroll
        for (int i = 0; i < M; ++i)
#pragma unroll
          for (int j = 0; j < N; ++j)
            acc[i][j] += a[i].x * w[j].x + a[i].y * w[j].y + a[i].z * w[j].z + a[i].w * w[j].w;
      }
    }
    __syncthreads();
  }

  if (G == 1) {
#pragma unroll
    for (int i = 0; i < M; ++i) {
      const int r = rq * M + i;
#pragma unroll
      for (int j = 0; j < N; ++j)
        writeOne(sm, bg, outMode, r >> 4, r & 15, c0 + cq * N + j, acc[i][j],
                 bias, Hdst, Edst, lofDst, lofC, pbase);
    }
  } else {
#pragma unroll
    for (int i = 0; i < M; ++i)
#pragma unroll
      for (int j = 0; j < N; ++j)
        sm->scr[(size_t)g * R * CW + (rq * M + i) * CW + cq * N + j] = acc[i][j];
    __syncthreads();
    for (int o = tid; o < R * CW; o += NT) {
      float s = 0.f;
#pragma unroll
      for (int gg = 0; gg < G; ++gg) s += sm->scr[gg * R * CW + o];
      const int r = o / CW, c = o % CW;
      writeOne(sm, bg, outMode, r >> 4, r & 15, c0 + c, s, bias, Hdst, Edst,
               lofDst, lofC, pbase);
    }
    __syncthreads();
  }
}

__global__ __launch_bounds__(NT, 4) void sc_coop(
    const int* __restrict__ info_bits, const float* __restrict__ rv,
    const int* __restrict__ info_set,
    const float* __restrict__ obs_emb, const float* __restrict__ label_emb,
    const float* __restrict__ cnW1, const float* __restrict__ cnb1,
    const float* __restrict__ cnW2, const float* __restrict__ cnb2,
    const float* __restrict__ bnW1, const float* __restrict__ bnb1,
    const float* __restrict__ bnW2, const float* __restrict__ bnb2,
    const float* __restrict__ llrW, const float* __restrict__ llrb,
    float* __restrict__ out, float* __restrict__ ws) {
  __shared__ SMem sm;
  const int tid = threadIdx.x;
  const int bid = blockIdx.x;
  const int bg = bid >> 4, cs = bid & 15;
  float* Ebuf = ws;
  float* Hbuf = ws + HBASE;
  unsigned* barp = (unsigned*)(ws + BAR_FOFF);
  unsigned* cnt = barp + bg;
  unsigned* gen = barp + 16 + bg;
  const float* obs2 = obs_emb + 2 * ND;

  // ---- block-local init: fmap + embC ----
  if (tid < 256) sm.fmap[tid] = -1;
  __syncthreads();
  if (tid < NK) sm.fmap[info_set[tid]] = tid;
  {
    const int bitv = tid >> 9, col = tid & 511;
    float s = 0.f;
#pragma unroll 4
    for (int j = 0; j < ND; ++j)
      s += label_emb[bitv * ND + j] * bnW1[(size_t)(NH + j) * NH + col];
    sm.emb[bitv * NH + col] = s;
  }
  __syncthreads();

  auto mlp = [&](int d, bool isBn) {
    const int P = 1 << (7 - d);
    const int CPc = P > 32 ? 32 : P;
    const float* srcE = (d == 0) ? nullptr : Ebuf + (size_t)loff(d) * NB * ND;
    const int lofDst = loff(d + 1);
    const float* W1 = isBn ? bnW1 : cnW1;
    const float* B1 = isBn ? bnb1 : cnb1;
    const float* W2 = isBn ? bnW2 : cnW2;
    const float* B2 = isBn ? bnb2 : cnb2;
    const int inM = (d == 0) ? 1 : 0;
    const int oM1 = isBn ? 1 : 0;
    for (int pb = 0; pb < P; pb += CPc) {
      switch (CPc) {
        case 32: phase_gemm<512,32,4,4,1, 32>(&sm,tid,bg,cs,inM,srcE,obs2,Hbuf,W1,NH,B1,oM1,Hbuf,nullptr,0,lofDst,pb); break;
        case 16: phase_gemm<256,32,4,2,1, 64>(&sm,tid,bg,cs,inM,srcE,obs2,Hbuf,W1,NH,B1,oM1,Hbuf,nullptr,0,lofDst,pb); break;
        case 8:  phase_gemm<128,32,2,2,1,128>(&sm,tid,bg,cs,inM,srcE,obs2,Hbuf,W1,NH,B1,oM1,Hbuf,nullptr,0,lofDst,pb); break;
        case 4:  phase_gemm< 64,32,2,2,2,256>(&sm,tid,bg,cs,inM,srcE,obs2,Hbuf,W1,NH,B1,oM1,Hbuf,nullptr,0,lofDst,pb); break;
        case 2:  phase_gemm< 32,32,2,2,4,256>(&sm,tid,bg,cs,inM,srcE,obs2,Hbuf,W1,NH,B1,oM1,Hbuf,nullptr,0,lofDst,pb); break;
        default: phase_gemm< 16,32,2,2,8,256>(&sm,tid,bg,cs,inM,srcE,obs2,Hbuf,W1,NH,B1,oM1,Hbuf,nullptr,0,lofDst,pb); break;
      }
      bgbar(cnt, gen);
      switch (CPc) {
        case 32: phase_gemm<512,16,4,4,2, 32>(&sm,tid,bg,cs,2,nullptr,obs2,Hbuf,W2,ND,B2,2,nullptr,Ebuf,lofDst,0,pb); break;
        case 16: phase_gemm<256,16,4,2,2, 64>(&sm,tid,bg,cs,2,nullptr,obs2,Hbuf,W2,ND,B2,2,nullptr,Ebuf,lofDst,0,pb); break;
        case 8:  phase_gemm<128,16,2,2,2,128>(&sm,tid,bg,cs,2,nullptr,obs2,Hbuf,W2,ND,B2,2,nullptr,Ebuf,lofDst,0,pb); break;
        case 4:  phase_gemm< 64,16,2,2,4,256>(&sm,tid,bg,cs,2,nullptr,obs2,Hbuf,W2,ND,B2,2,nullptr,Ebuf,lofDst,0,pb); break;
        case 2:  phase_gemm< 32,16,2,2,8,256>(&sm,tid,bg,cs,2,nullptr,obs2,Hbuf,W2,ND,B2,2,nullptr,Ebuf,lofDst,0,pb); break;
        default: phase_gemm< 16,16,2,1,8,256>(&sm,tid,bg,cs,2,nullptr,obs2,Hbuf,W2,ND,B2,2,nullptr,Ebuf,lofDst,0,pb); break;
      }
      bgbar(cnt, gen);
    }
  };

  auto decide = [&](int off) {
    const int w = tid >> 6, lane = tid & 63;
    const int b = bg * 16 + w;
    const float* e8 = Ebuf + (size_t)254 * NB * ND + (size_t)b * ND;
    const float4 e4 = *(const float4*)&e8[lane * 4];
    const float4 wA = *(const float4*)&llrW[lane * 8];
    const float4 wB = *(const float4*)&llrW[lane * 8 + 4];
    float l0 = e4.x * wA.x + e4.y * wA.z + e4.z * wB.x + e4.w * wB.z;
    float l1 = e4.x * wA.y + e4.y * wA.w + e4.z * wB.y + e4.w * wB.w;
#pragma unroll
    for (int o = 1; o < 64; o <<= 1) {
      l0 += __shfl_xor(l0, o);
      l1 += __shfl_xor(l1, o);
    }
    l0 += llrb[0]; l1 += llrb[1];
    const float mx = fmaxf(l0, l1);
    const float ee0 = expf(l0 - mx), ee1 = expf(l1 - mx);
    const float p0 = ee0 / (ee0 + ee1), p1 = ee1 / (ee0 + ee1);
    const int hard = (rv[b * NN + off] > p0) ? 1 : 0;
    const int fidx = sm.fmap[off];
    const int fval = (fidx >= 0) ? info_bits[b * NK + fidx] : 2;
    const int xb = (fval == 2) ? hard : fval;
    int* cur = (int*)sm.scr;
    int* nxt = cur + 4096;
    if (cs == 0 && lane == 0) {
      out[OUT_F + b * NN + off] = (fidx >= 0) ? 2.0f : (float)xb;
      out[OUT_U + b * NN + off] = (float)xb;
      out[OUT_P + (b * NN + off) * 2 + 0] = p0;
      out[OUT_P + (b * NN + off) * 2 + 1] = p1;
    }
    if (lane == 0) cur[w * 256] = xb;
    __syncthreads();
    int idx = off, len = 1, lev = 8;
    while (idx & 1) {
      for (int i = lane; i < len; i += 64) {
        const int c = cur[w * 256 + i];
        nxt[w * 256 + 2 * i] = sm.L[w * 256 + loff(lev) + i] ^ c;
        nxt[w * 256 + 2 * i + 1] = c;
      }
      __syncthreads();
      int* t = cur; cur = nxt; nxt = t;
      len <<= 1; idx >>= 1; --lev;
    }
    if (lev > 0) {
      for (int i = lane; i < len; i += 64) sm.L[w * 256 + loff(lev) + i] = cur[w * 256 + i];
    } else if (cs == 0) {
      for (int i = lane; i < len; i += 64) out[OUT_X + b * NN + i] = (float)cur[w * 256 + i];
    }
    __syncthreads();
  };

  // ---- schedule ----
  for (int d = 0; d < 8; ++d) mlp(d, false);
  for (int off = 0; off < NN; ++off) {
    decide(off);
    if (off < NN - 1) {
      const int z = __ffs(off + 1) - 1;
      const int dbn = 7 - z;
      mlp(dbn, true);
      for (int d2 = dbn + 1; d2 < 8; ++d2) mlp(d2, false);
    }
  }
}

extern "C" void kernel_launch(void* const* d_in, const int* in_sizes, int n_in,
                              void* d_out, int out_size, void* d_ws, size_t ws_size,
                              hipStream_t stream) {
  const int*   info_bits = (const int*)d_in[0];
  const float* rv        = (const float*)d_in[1];
  const int*   info_set  = (const int*)d_in[2];
  const float* obs_emb   = (const float*)d_in[3];
  const float* label_emb = (const float*)d_in[4];
  const float* cnW1      = (const float*)d_in[5];
  const float* cnb1      = (const float*)d_in[6];
  const float* cnW2      = (const float*)d_in[7];
  const float* cnb2      = (const float*)d_in[8];
  const float* bnW1      = (const float*)d_in[9];
  const float* bnb1      = (const float*)d_in[10];
  const float* bnW2      = (const float*)d_in[11];
  const float* bnb2      = (const float*)d_in[12];
  const float* llrW      = (const float*)d_in[13];
  const float* llrb      = (const float*)d_in[14];

  float* out = (float*)d_out;
  float* ws  = (float*)d_ws;

  // zero barrier state (cnt[16] + gen[16])
  hipMemsetAsync((char*)d_ws + (size_t)BAR_FOFF * 4, 0, 128, stream);

  void* args[] = {
      (void*)&info_bits, (void*)&rv, (void*)&info_set, (void*)&obs_emb,
      (void*)&label_emb, (void*)&cnW1, (void*)&cnb1, (void*)&cnW2, (void*)&cnb2,
      (void*)&bnW1, (void*)&bnb1, (void*)&bnW2, (void*)&bnb2,
      (void*)&llrW, (void*)&llrb, (void*)&out, (void*)&ws};
  hipLaunchCooperativeKernel((const void*)sc_coop, dim3(256), dim3(NT), args, 0,
                             stream);
}

// Round 6
// 19148.462 us; speedup vs baseline: 7.8025x; 7.8025x over previous
//
#include <hip/hip_runtime.h>
#include <math.h>

#define NB 256
#define NN 256
#define NK 128
#define ND 256
#define NH 512
#define NT 1024

// output layout (floats): x | f_out | u | p_u
#define OUT_X 0
#define OUT_F 65536
#define OUT_U 131072
#define OUT_P 196608

// per-batch ws layout (float offsets)
#define EPB   65280              // E slabs levels 1..8 (255*256)
#define SP4O  (EPB)              // spec d4: 8*2*256
#define SP5O  (SP4O + 4096)      // 4*2*256
#define SP6O  (SP5O + 2048)      // 2*2*256
#define S1O   (SP6O + 1024)      // 2*256
#define S2O   (S1O + 512)        // 4*256
#define S3O   (S2O + 1024)       // 8*256
#define LOFFI (S3O + 2048)       // 256 ints (decision-bit slabs)
#define BPB   (LOFFI + 256)      // floats per batch

__host__ __device__ __forceinline__ int loff(int d) { return 256 - (1 << (9 - d)); }

struct SMem {
  float scr[18432];   // G1: inS[0..8320) + part1[8320..16512) ; G2: part2[0..18432)
  float hid[24 * 512];
  float emb[2 * 512];  // label_emb[bit] @ bnW1[512:768]
  float* rowDst[24];
  int cur[256], nxt[256];
  float red[8];
  int qb[4];
  int bitR[16];
  int fmap[256];
};

// ---------- GEMM1: pre = A[R][512] x W[512][C]; writes hid rows ----------
// MODE 0: plain cn (C=512, ReLU+cnb1) ; 1: plain bn (C=512, +embC[bitR]) ;
// 2: fused (C=1024: cols<512 cn-hid, cols>=512 bn-base -> 2 ReLU variants)
template <int R, int MODE>
__device__ void g1(SMem* sm, int tid,
                   const float* __restrict__ Wcn, const float* __restrict__ Wbn,
                   const float* __restrict__ b1a, const float* __restrict__ b1b) {
  constexpr int C = (MODE == 2) ? 1024 : 512;
  constexpr int NCC = (MODE == 2) ? 2 : 1;
  const int half = tid >> 9;
  const int cg = tid & 511;
  const int c0 = cg * NCC;
  const float* Wp;
  if (MODE == 2) Wp = (c0 < 512) ? (Wcn + c0) : (Wbn + (c0 - 512));
  else Wp = ((MODE == 0) ? Wcn : Wbn) + c0;

  float acc[R][NCC];
#pragma unroll
  for (int r = 0; r < R; ++r)
#pragma unroll
    for (int n = 0; n < NCC; ++n) acc[r][n] = 0.f;

  const int kb = half * 256;
  for (int kc = 0; kc < 256; kc += 4) {
    const int k = kb + kc;
    float w[4][NCC];
#pragma unroll
    for (int j = 0; j < 4; ++j) {
      if (NCC == 2) {
        const float2 wv = *(const float2*)&Wp[(size_t)(k + j) * NH];
        w[j][0] = wv.x; w[j][1] = wv.y;
      } else {
        w[j][0] = Wp[(size_t)(k + j) * NH];
      }
    }
#pragma unroll
    for (int r = 0; r < R; ++r) {
      const float4 a = *(const float4*)&sm->scr[r * 520 + k];
#pragma unroll
      for (int n = 0; n < NCC; ++n)
        acc[r][n] += a.x * w[0][n] + a.y * w[1][n] + a.z * w[2][n] + a.w * w[3][n];
    }
  }
  float* part1 = sm->scr + 8320;
  if (half == 1) {
#pragma unroll
    for (int r = 0; r < R; ++r)
#pragma unroll
      for (int n = 0; n < NCC; ++n) part1[r * C + c0 + n] = acc[r][n];
  }
  __syncthreads();
  if (half == 0) {
#pragma unroll
    for (int r = 0; r < R; ++r) {
#pragma unroll
      for (int n = 0; n < NCC; ++n) {
        const int c = c0 + n;
        const float pre = acc[r][n] + part1[r * C + c];
        if (MODE == 2) {
          if (c < 512) {
            sm->hid[r * 512 + c] = fmaxf(pre + b1a[c], 0.f);
          } else {
            const int cb = c - 512;
            const float base = pre + b1b[cb];
            sm->hid[(R + 2 * r) * 512 + cb] = fmaxf(base + sm->emb[cb], 0.f);
            sm->hid[(R + 2 * r + 1) * 512 + cb] = fmaxf(base + sm->emb[512 + cb], 0.f);
          }
        } else if (MODE == 0) {
          sm->hid[r * 512 + c] = fmaxf(pre + b1a[c], 0.f);
        } else {
          sm->hid[r * 512 + c] = fmaxf(pre + b1a[c] + sm->emb[sm->bitR[r] * 512 + c], 0.f);
        }
      }
    }
  }
  __syncthreads();
}

// ---------- GEMM2: out = hid[RT][512] x W2[512][256] + bias -> rowDst ----------
// rows [0,RCN) use cnW2/cnb2; rows [RCN,RT) use bnW2/bnb2.
template <int RT, int RCN>
__device__ void g2(SMem* sm, int tid,
                   const float* __restrict__ Wcn2, const float* __restrict__ Wbn2,
                   const float* __restrict__ bcn2, const float* __restrict__ bbn2) {
  const int c = tid & 255;
  const int g = tid >> 8;  // 0..3, k-slice of 128
  const int kb = g * 128;
  float acc[RT];
#pragma unroll
  for (int r = 0; r < RT; ++r) acc[r] = 0.f;

  for (int kc = 0; kc < 128; kc += 4) {
    const int k = kb + kc;
    float wc[4], wb[4];
    if constexpr (RCN > 0) {
#pragma unroll
      for (int j = 0; j < 4; ++j) wc[j] = Wcn2[(size_t)(k + j) * ND + c];
    }
    if constexpr (RCN < RT) {
#pragma unroll
      for (int j = 0; j < 4; ++j) wb[j] = Wbn2[(size_t)(k + j) * ND + c];
    }
#pragma unroll
    for (int r = 0; r < RT; ++r) {
      const float4 a = *(const float4*)&sm->hid[r * 512 + k];
      if (r < RCN)
        acc[r] += a.x * wc[0] + a.y * wc[1] + a.z * wc[2] + a.w * wc[3];
      else
        acc[r] += a.x * wb[0] + a.y * wb[1] + a.z * wb[2] + a.w * wb[3];
    }
  }
  float* part2 = sm->scr;
  if (g > 0) {
#pragma unroll
    for (int r = 0; r < RT; ++r) part2[((g - 1) * RT + r) * 256 + c] = acc[r];
  }
  __syncthreads();
  if (g == 0) {
#pragma unroll
    for (int r = 0; r < RT; ++r) {
      float s = acc[r] + part2[(0 * RT + r) * 256 + c] + part2[(1 * RT + r) * 256 + c] +
                part2[(2 * RT + r) * 256 + c];
      s += (r < RCN) ? bcn2[c] : bbn2[c];
      sm->rowDst[r][c] = s;
    }
  }
  __syncthreads();
}

// ---------- A staging ----------
__device__ __forceinline__ void stageA_pairs(SMem* sm, int tid, const float* __restrict__ Ed,
                                             const float* __restrict__ obs2, int p0, int R) {
  const int nf4 = R * 128;
  for (int i = tid; i < nf4; i += NT) {
    const int r = i >> 7, q = i & 127;
    const int k = q * 4;
    float4 v;
    if (Ed == nullptr) v = *(const float4*)&obs2[k & 255];
    else v = *(const float4*)&Ed[(size_t)(2 * (p0 + r) + (k >> 8)) * ND + (k & 255)];
    *(float4*)&sm->scr[r * 520 + k] = v;
  }
}

__device__ __forceinline__ void stageA_d7(SMem* sm, int tid, const float* __restrict__ E,
                                          const float* __restrict__ sp6) {
  for (int i = tid; i < 5 * 128; i += NT) {
    const int r = i >> 7, q = i & 127;
    const int k = q * 4;
    const int h = k >> 8;
    const float* src;
    if (r == 0) src = E + (size_t)(252 + h) * ND;
    else {
      const int cc = r - 1;
      const int bit = (h == 0) ? (cc >> 1) : (cc & 1);
      src = sp6 + (size_t)(h * 2 + bit) * ND;
    }
    *(float4*)&sm->scr[r * 520 + k] = *(const float4*)&src[k & 255];
  }
}

__global__ __launch_bounds__(NT, 1) void sc_spec(
    const int* __restrict__ info_bits, const float* __restrict__ rv,
    const int* __restrict__ info_set,
    const float* __restrict__ obs_emb, const float* __restrict__ label_emb,
    const float* __restrict__ cnW1, const float* __restrict__ cnb1,
    const float* __restrict__ cnW2, const float* __restrict__ cnb2,
    const float* __restrict__ bnW1, const float* __restrict__ bnb1,
    const float* __restrict__ bnW2, const float* __restrict__ bnb2,
    const float* __restrict__ llrW, const float* __restrict__ llrb,
    float* __restrict__ out, float* __restrict__ ws) {
  __shared__ SMem sm;
  const int tid = threadIdx.x, b = blockIdx.x;
  float* wsb = ws + (size_t)b * BPB;
  float* E = wsb;
  float* sp4 = wsb + SP4O;
  float* sp5 = wsb + SP5O;
  float* sp6 = wsb + SP6O;
  float* S1 = wsb + S1O;
  float* S2 = wsb + S2O;
  float* S3 = wsb + S3O;
  int* Lb = (int*)(wsb + LOFFI);
  const float* obs2 = obs_emb + 2 * ND;

  // ---- init: embC + fmap ----
  {
    const int bit = tid >> 9, col = tid & 511;
    float s = 0.f;
#pragma unroll 4
    for (int j = 0; j < ND; ++j)
      s += label_emb[bit * ND + j] * bnW1[(size_t)(NH + j) * NH + col];
    sm.emb[bit * 512 + col] = s;
  }
  if (tid < 256) sm.fmap[tid] = -1;
  __syncthreads();
  if (tid < NK) sm.fmap[info_set[tid]] = tid;
  __syncthreads();

  auto plainPass = [&](int d, bool isBn, int p0) {
    const float* Ed = (d == 0) ? nullptr : E + (size_t)loff(d) * ND;
    float* dstE = E + (size_t)loff(d + 1) * ND;
    stageA_pairs(&sm, tid, Ed, obs2, p0, 16);
    if (isBn && tid < 16) sm.bitR[tid] = Lb[loff(d + 1) + p0 + tid];
    if (tid < 16) sm.rowDst[tid] = dstE + (size_t)(p0 + tid) * ND;
    __syncthreads();
    if (!isBn) {
      g1<16, 0>(&sm, tid, cnW1, nullptr, cnb1, nullptr);
      g2<16, 16>(&sm, tid, cnW2, nullptr, cnb2, nullptr);
    } else {
      g1<16, 1>(&sm, tid, nullptr, bnW1, bnb1, nullptr);
      g2<16, 0>(&sm, tid, nullptr, bnW2, nullptr, bnb2);
    }
  };

  auto fusedPass = [&](int d) {
    const int P = 1 << (7 - d);  // 8,4,2
    const float* Ed = E + (size_t)loff(d) * ND;
    float* dstE = E + (size_t)loff(d + 1) * ND;
    float* spd = (d == 4) ? sp4 : (d == 5) ? sp5 : sp6;
    stageA_pairs(&sm, tid, Ed, obs2, 0, P);
    if (tid < 3 * P)
      sm.rowDst[tid] = (tid < P) ? (dstE + (size_t)tid * ND) : (spd + (size_t)(tid - P) * ND);
    __syncthreads();
    if (d == 4) {
      g1<8, 2>(&sm, tid, cnW1, bnW1, cnb1, bnb1);
      g2<24, 8>(&sm, tid, cnW2, bnW2, cnb2, bnb2);
    } else if (d == 5) {
      g1<4, 2>(&sm, tid, cnW1, bnW1, cnb1, bnb1);
      g2<12, 4>(&sm, tid, cnW2, bnW2, cnb2, bnb2);
    } else {
      g1<2, 2>(&sm, tid, cnW1, bnW1, cnb1, bnb1);
      g2<6, 2>(&sm, tid, cnW2, bnW2, cnb2, bnb2);
    }
  };

  auto d7comb = [&]() {
    stageA_d7(&sm, tid, E, sp6);
    if (tid < 15) {
      float* dst;
      if (tid == 0) dst = E + (size_t)254 * ND;
      else if (tid < 5) dst = S2 + (size_t)(tid - 1) * ND;
      else if (tid < 7) dst = S1 + (size_t)(tid - 5) * ND;
      else dst = S3 + (size_t)(tid - 7) * ND;
      sm.rowDst[tid] = dst;
    }
    __syncthreads();
    g1<5, 2>(&sm, tid, cnW1, bnW1, cnb1, bnb1);
    g2<15, 5>(&sm, tid, cnW2, bnW2, cnb2, bnb2);
  };

  auto selectSpec = [&](int d) {  // d in {4,5}
    const int P = 1 << (7 - d);
    const float* spd = (d == 4) ? sp4 : sp5;
    float* dstE = E + (size_t)loff(d + 1) * ND;
    for (int i = tid; i < P * ND; i += NT) {
      const int p = i >> 8, c = i & 255;
      const int bit = Lb[loff(d + 1) + p];
      dstE[p * ND + c] = spd[(size_t)(p * 2 + bit) * ND + c];
    }
    __syncthreads();
  };

  auto leaf = [&](int off, const float* src) {
    if (tid < 256) {
      const float ev = src[tid];
      float v0 = ev * llrW[2 * tid];
      float v1 = ev * llrW[2 * tid + 1];
#pragma unroll
      for (int o = 32; o > 0; o >>= 1) {
        v0 += __shfl_down(v0, o);
        v1 += __shfl_down(v1, o);
      }
      if ((tid & 63) == 0) {
        sm.red[tid >> 6] = v0;
        sm.red[4 + (tid >> 6)] = v1;
      }
    }
    __syncthreads();
    if (tid == 0) {
      const float l0 = sm.red[0] + sm.red[1] + sm.red[2] + sm.red[3] + llrb[0];
      const float l1 = sm.red[4] + sm.red[5] + sm.red[6] + sm.red[7] + llrb[1];
      const float m = fmaxf(l0, l1);
      const float e0 = expf(l0 - m), e1 = expf(l1 - m);
      const float s = e0 + e1;
      const float p0 = e0 / s, p1 = e1 / s;
      const int hard = (rv[b * NN + off] > p0) ? 1 : 0;
      const int fidx = sm.fmap[off];
      const int fval = (fidx >= 0) ? info_bits[b * NK + fidx] : 2;
      const int xb = (fval == 2) ? hard : fval;
      out[OUT_F + b * NN + off] = (fidx >= 0) ? 2.0f : (float)xb;
      out[OUT_U + b * NN + off] = (float)xb;
      out[OUT_P + (b * NN + off) * 2 + 0] = p0;
      out[OUT_P + (b * NN + off) * 2 + 1] = p1;
      sm.cur[0] = xb;
      sm.qb[off & 3] = xb;
    }
    __syncthreads();
    int* cur = sm.cur;
    int* nxt = sm.nxt;
    int len = 1, lev = 8, idx = off;
    while (idx & 1) {
      if (tid < len) {
        const int c = cur[tid];
        nxt[2 * tid] = Lb[loff(lev) + tid] ^ c;
        nxt[2 * tid + 1] = c;
      }
      __syncthreads();
      int* t = cur; cur = nxt; nxt = t;
      len <<= 1; idx >>= 1; --lev;
    }
    if (lev > 0) {
      if (tid < len) Lb[loff(lev) + tid] = cur[tid];
    } else {
      if (tid < 256) out[OUT_X + b * NN + tid] = (float)cur[tid];
    }
    __syncthreads();
  };

  // ---- initial descent ----
  for (int d = 0; d < 4; ++d)
    for (int p0 = 0; p0 < (1 << (7 - d)); p0 += 16) plainPass(d, false, p0);
  fusedPass(4); fusedPass(5); fusedPass(6);
  d7comb();

  // ---- leaf loop ----
  for (int off = 0; off < NN; ++off) {
    const int ph = off & 3;
    const float* src;
    if (ph == 0) src = E + (size_t)254 * ND;
    else if (ph == 1) src = S1 + (size_t)sm.qb[0] * ND;
    else {
      const int cidx = 2 * (sm.qb[0] ^ sm.qb[1]) + sm.qb[1];
      src = (ph == 2) ? (S2 + (size_t)cidx * ND) : (S3 + (size_t)(2 * cidx + sm.qb[2]) * ND);
    }
    leaf(off, src);
    if (off == NN - 1) break;
    const int t = off + 1;
    const int z = __ffs(t) - 1;
    if (z <= 1) continue;  // inside a size-4 quad: everything speculated
    const int dbn = 7 - z;  // <= 5
    if (dbn >= 4) {
      selectSpec(dbn);
    } else {
      for (int p0 = 0; p0 < (1 << (7 - dbn)); p0 += 16) plainPass(dbn, true, p0);
    }
    for (int d = dbn + 1; d < 4; ++d)
      for (int p0 = 0; p0 < (1 << (7 - d)); p0 += 16) plainPass(d, false, p0);
    for (int d = (dbn + 1 > 4 ? dbn + 1 : 4); d < 7; ++d) fusedPass(d);
    d7comb();
  }
}

extern "C" void kernel_launch(void* const* d_in, const int* in_sizes, int n_in,
                              void* d_out, int out_size, void* d_ws, size_t ws_size,
                              hipStream_t stream) {
  const int*   info_bits = (const int*)d_in[0];
  const float* rv        = (const float*)d_in[1];
  const int*   info_set  = (const int*)d_in[2];
  const float* obs_emb   = (const float*)d_in[3];
  const float* label_emb = (const float*)d_in[4];
  const float* cnW1      = (const float*)d_in[5];
  const float* cnb1      = (const float*)d_in[6];
  const float* cnW2      = (const float*)d_in[7];
  const float* cnb2      = (const float*)d_in[8];
  const float* bnW1      = (const float*)d_in[9];
  const float* bnb1      = (const float*)d_in[10];
  const float* bnW2      = (const float*)d_in[11];
  const float* bnb2      = (const float*)d_in[12];
  const float* llrW      = (const float*)d_in[13];
  const float* llrb      = (const float*)d_in[14];

  float* out = (float*)d_out;
  float* ws  = (float*)d_ws;

  sc_spec<<<dim3(NB), dim3(NT), 0, stream>>>(
      info_bits, rv, info_set, obs_emb, label_emb,
      cnW1, cnb1, cnW2, cnb2, bnW1, bnb1, bnW2, bnb2,
      llrW, llrb, out, ws);
}